// Round 1
// baseline (262.438 us; speedup 1.0000x reference)
//
#include <hip/hip_runtime.h>

// Problem constants (fixed by the reference setup)
#define B_ROWS 8192
#define K_DIM  1024
#define N_COLS 4096

typedef __attribute__((ext_vector_type(8))) __bf16 bf16x8;
typedef __attribute__((ext_vector_type(4))) float  f32x4;

typedef const __attribute__((address_space(1))) void global_void;
typedef __attribute__((address_space(3))) void lds_void;

__device__ inline unsigned short f2bf(float f) {
  unsigned int u = __float_as_uint(f);
  u += 0x7FFFu + ((u >> 16) & 1u);   // round-to-nearest-even
  return (unsigned short)(u >> 16);
}

// ---------------- prep kernels ----------------

// One block per row: convert x row to bf16 + compute ||x||^2.
__global__ __launch_bounds__(256) void prep_x(const float* __restrict__ x,
                                              unsigned short* __restrict__ xb,
                                              float* __restrict__ xsq) {
  const int row = blockIdx.x;
  const int tid = threadIdx.x;
  const float4 v = reinterpret_cast<const float4*>(x + (size_t)row * K_DIM)[tid];
  ushort4 o;
  o.x = f2bf(v.x); o.y = f2bf(v.y); o.z = f2bf(v.z); o.w = f2bf(v.w);
  reinterpret_cast<ushort4*>(xb + (size_t)row * K_DIM)[tid] = o;
  float s = v.x * v.x + v.y * v.y + v.z * v.z + v.w * v.w;
#pragma unroll
  for (int off = 32; off > 0; off >>= 1) s += __shfl_down(s, off);
  __shared__ float red[4];
  if ((tid & 63) == 0) red[tid >> 6] = s;
  __syncthreads();
  if (tid == 0) xsq[row] = red[0] + red[1] + red[2] + red[3];
}

// Transpose + convert mu (K x N fp32, row-major) -> muT (N x K bf16, row-major)
__global__ __launch_bounds__(256) void prep_mu(const float* __restrict__ mu,
                                               unsigned short* __restrict__ muT) {
  __shared__ float tile[32][33];
  const int k0 = blockIdx.x * 32;  // K
  const int n0 = blockIdx.y * 32;  // N
  const int tx = threadIdx.x;      // 0..31
  const int ty = threadIdx.y;      // 0..7
#pragma unroll
  for (int r = 0; r < 32; r += 8)
    tile[r + ty][tx] = mu[(size_t)(k0 + r + ty) * N_COLS + n0 + tx];
  __syncthreads();
#pragma unroll
  for (int r = 0; r < 32; r += 8)
    muT[(size_t)(n0 + r + ty) * K_DIM + k0 + tx] = f2bf(tile[tx][r + ty]);
}

// Per-column ||mu||^2; block = 64 cols x 4 k-strips, coalesced.
__global__ __launch_bounds__(256) void musq_k(const float* __restrict__ mu,
                                              float* __restrict__ musq) {
  __shared__ float red[4][64];
  const int tx = threadIdx.x & 63;
  const int ty = threadIdx.x >> 6;
  const int u = blockIdx.x * 64 + tx;
  float s = 0.f;
  for (int k = ty * 256; k < (ty + 1) * 256; ++k) {
    float v = mu[(size_t)k * N_COLS + u];
    s += v * v;
  }
  red[ty][tx] = s;
  __syncthreads();
  if (ty == 0) musq[u] = red[0][tx] + red[1][tx] + red[2][tx] + red[3][tx];
}

// ---------------- main GEMM + epilogue ----------------
// 128x128 tile, 256 threads = 4 waves in 2x2, each wave does 64x64 via
// 4x4 grid of 16x16x32 bf16 MFMA. BK=32. global_load_lds width-16 staging.

#define BM 128
#define BN 128
#define BK 32

__global__ __launch_bounds__(256) void rbf_gemm(
    const unsigned short* __restrict__ xb,   // B_ROWS x K_DIM bf16 bits
    const unsigned short* __restrict__ muT,  // N_COLS x K_DIM bf16 bits
    const float* __restrict__ xsq, const float* __restrict__ musq,
    const float* __restrict__ gamma_p, float* __restrict__ out) {
  __shared__ unsigned short la[BM * BK];  // 8 KB
  __shared__ unsigned short lb[BN * BK];  // 8 KB
  const int tid = threadIdx.x;
  const int bm0 = blockIdx.x * BM;
  const int bn0 = blockIdx.y * BN;
  const int w = tid >> 6, l = tid & 63;
  const int wm = (w >> 1) * 64, wn = (w & 1) * 64;
  const int l15 = l & 15, l4 = l >> 4;

  f32x4 acc[4][4] = {};

  // staging: thread t covers LDS bytes [t*16, t*16+16) => row t/4, k-chunk (t%4)*8
  const int srow = tid >> 2;
  const int schunk = (tid & 3) * 8;
  const unsigned short* ga = xb + (size_t)(bm0 + srow) * K_DIM + schunk;
  const unsigned short* gb = muT + (size_t)(bn0 + srow) * K_DIM + schunk;
  unsigned short* la_dst = &la[tid * 8];
  unsigned short* lb_dst = &lb[tid * 8];

  for (int kk = 0; kk < K_DIM; kk += BK) {
    __builtin_amdgcn_global_load_lds((global_void*)(ga + kk),
                                     (lds_void*)la_dst, 16, 0, 0);
    __builtin_amdgcn_global_load_lds((global_void*)(ga + (size_t)64 * K_DIM + kk),
                                     (lds_void*)(la_dst + 64 * BK), 16, 0, 0);
    __builtin_amdgcn_global_load_lds((global_void*)(gb + kk),
                                     (lds_void*)lb_dst, 16, 0, 0);
    __builtin_amdgcn_global_load_lds((global_void*)(gb + (size_t)64 * K_DIM + kk),
                                     (lds_void*)(lb_dst + 64 * BK), 16, 0, 0);
    __syncthreads();  // drains vmcnt for global_load_lds + barrier

    bf16x8 af[4], bfr[4];
#pragma unroll
    for (int t = 0; t < 4; ++t) {
      af[t]  = *reinterpret_cast<const bf16x8*>(&la[(wm + t * 16 + l15) * BK + l4 * 8]);
      bfr[t] = *reinterpret_cast<const bf16x8*>(&lb[(wn + t * 16 + l15) * BK + l4 * 8]);
    }
#pragma unroll
    for (int mt = 0; mt < 4; ++mt)
#pragma unroll
      for (int nt = 0; nt < 4; ++nt)
        acc[mt][nt] = __builtin_amdgcn_mfma_f32_16x16x32_bf16(af[mt], bfr[nt],
                                                              acc[mt][nt], 0, 0, 0);
    __syncthreads();
  }

  const float g = gamma_p[0];
#pragma unroll
  for (int mt = 0; mt < 4; ++mt) {
    const int gm0 = bm0 + wm + mt * 16 + l4 * 4;
#pragma unroll
    for (int nt = 0; nt < 4; ++nt) {
      const int gn = bn0 + wn + nt * 16 + l15;
      const float ms = musq[gn];
#pragma unroll
      for (int r = 0; r < 4; ++r) {
        const int gm = gm0 + r;
        const float l2 = xsq[gm] + ms - 2.0f * acc[mt][nt][r];
        out[(size_t)gm * N_COLS + gn] = __expf(-g * l2);
      }
    }
  }
}

// ---------------- fallback (ws too small; fp32 direct) ----------------
__global__ __launch_bounds__(256) void rbf_naive(const float* __restrict__ x,
                                                 const float* __restrict__ mu,
                                                 const float* __restrict__ gp,
                                                 float* __restrict__ out) {
  const int u = blockIdx.x * 256 + threadIdx.x;
  const int b = blockIdx.y;
  const float* xr = x + (size_t)b * K_DIM;
  float dot = 0.f, xs = 0.f, ms = 0.f;
  for (int k = 0; k < K_DIM; ++k) {
    const float xv = xr[k];
    const float mv = mu[(size_t)k * N_COLS + u];
    dot += xv * mv; xs += xv * xv; ms += mv * mv;
  }
  out[(size_t)b * N_COLS + u] = __expf(-gp[0] * (xs + ms - 2.f * dot));
}

extern "C" void kernel_launch(void* const* d_in, const int* in_sizes, int n_in,
                              void* d_out, int out_size, void* d_ws, size_t ws_size,
                              hipStream_t stream) {
  const float* x  = (const float*)d_in[0];
  const float* mu = (const float*)d_in[1];
  const float* gp = (const float*)d_in[2];
  float* out = (float*)d_out;

  const size_t xb_bytes  = (size_t)B_ROWS * K_DIM * 2;  // 16 MB
  const size_t mut_bytes = (size_t)N_COLS * K_DIM * 2;  //  8 MB
  const size_t need = xb_bytes + mut_bytes + B_ROWS * 4 + N_COLS * 4;

  if (ws_size < need) {
    rbf_naive<<<dim3(N_COLS / 256, B_ROWS), 256, 0, stream>>>(x, mu, gp, out);
    return;
  }

  unsigned short* xb  = (unsigned short*)d_ws;
  unsigned short* muT = (unsigned short*)((char*)d_ws + xb_bytes);
  float* xsq  = (float*)((char*)d_ws + xb_bytes + mut_bytes);
  float* musq = xsq + B_ROWS;

  prep_x<<<B_ROWS, 256, 0, stream>>>(x, xb, xsq);
  prep_mu<<<dim3(K_DIM / 32, N_COLS / 32), dim3(32, 8), 0, stream>>>(mu, muT);
  musq_k<<<N_COLS / 64, 256, 0, stream>>>(mu, musq);
  rbf_gemm<<<dim3(B_ROWS / BM, N_COLS / BN), 256, 0, stream>>>(xb, muT, xsq, musq, gp, out);
}

// Round 2
// 217.857 us; speedup vs baseline: 1.2046x; 1.2046x over previous
//
#include <hip/hip_runtime.h>

// Problem constants (fixed by the reference setup)
#define B_ROWS 8192
#define K_DIM  1024
#define N_COLS 4096

// exp(-t) == 0.0f (below smallest subnormal 2^-149) for t > 150*ln2 = 103.97.
// Use 120 for margin against fp error in the norm computation.
#define UNDERFLOW_T 120.0f

typedef __attribute__((ext_vector_type(8))) __bf16 bf16x8;
typedef __attribute__((ext_vector_type(4))) float  f32x4;

typedef const __attribute__((address_space(1))) void global_void;
typedef __attribute__((address_space(3))) void lds_void;

__device__ inline unsigned short f2bf(float f) {
  unsigned int u = __float_as_uint(f);
  u += 0x7FFFu + ((u >> 16) & 1u);   // round-to-nearest-even
  return (unsigned short)(u >> 16);
}

// ---------------- norm kernels (always run; feed the underflow bound) -------

// One wave per row of x: ||x_row||^2. grid = B_ROWS/4 blocks of 256.
__global__ __launch_bounds__(256) void xsq_k(const float* __restrict__ x,
                                             float* __restrict__ xsq) {
  const int row  = (blockIdx.x * 256 + threadIdx.x) >> 6;
  const int lane = threadIdx.x & 63;
  const float4* xr = reinterpret_cast<const float4*>(x + (size_t)row * K_DIM);
  float s = 0.f;
#pragma unroll
  for (int i = 0; i < 4; ++i) {
    const float4 v = xr[lane + i * 64];
    s += v.x * v.x + v.y * v.y + v.z * v.z + v.w * v.w;
  }
#pragma unroll
  for (int off = 32; off; off >>= 1) s += __shfl_down(s, off);
  if (lane == 0) xsq[row] = s;
}

// Partial per-column ||mu||^2 over a K-quarter. grid (64, 4), block 256.
// No atomics: block (cg, kq) writes part[kq][cg*64 .. cg*64+64).
__global__ __launch_bounds__(256) void musq_part_k(const float* __restrict__ mu,
                                                   float* __restrict__ part) {
  const int tx = threadIdx.x & 63;   // col within group
  const int ty = threadIdx.x >> 6;   // strip within quarter
  const int u  = blockIdx.x * 64 + tx;
  const int k0 = blockIdx.y * 256 + ty * 64;
  float s = 0.f;
  for (int k = k0; k < k0 + 64; ++k) {
    const float v = mu[(size_t)k * N_COLS + u];
    s += v * v;
  }
  __shared__ float red[4][64];
  red[ty][tx] = s;
  __syncthreads();
  if (ty == 0)
    part[(size_t)blockIdx.y * N_COLS + u] =
        red[0][tx] + red[1][tx] + red[2][tx] + red[3][tx];
}

// Combine quarters: musq[u] = sum_kq part[kq][u]. grid 16 blocks of 256.
__global__ __launch_bounds__(256) void musq_sum_k(const float* __restrict__ part,
                                                  float* __restrict__ musq) {
  const int u = blockIdx.x * 256 + threadIdx.x;
  musq[u] = part[u] + part[N_COLS + u] + part[2 * N_COLS + u] + part[3 * N_COLS + u];
}

// Single block: flag = (min||x|| > max||mu||) && gamma*(min||x||-max||mu||)^2 > T.
// If set, every output provably underflows to exactly 0.0f (Cauchy-Schwarz:
// l2 >= (||x||-||mu||)^2 for every pair).
__global__ __launch_bounds__(256) void flag_k(const float* __restrict__ xsq,
                                              const float* __restrict__ musq,
                                              const float* __restrict__ gp,
                                              int* __restrict__ flag) {
  const int tid = threadIdx.x;
  float mn = 3.4e38f, mx = 0.f;
  for (int i = tid; i < B_ROWS; i += 256) mn = fminf(mn, xsq[i]);
  for (int i = tid; i < N_COLS; i += 256) mx = fmaxf(mx, musq[i]);
  __shared__ float smn[256], smx[256];
  smn[tid] = mn; smx[tid] = mx;
  __syncthreads();
  for (int s = 128; s; s >>= 1) {
    if (tid < s) {
      smn[tid] = fminf(smn[tid], smn[tid + s]);
      smx[tid] = fmaxf(smx[tid], smx[tid + s]);
    }
    __syncthreads();
  }
  if (tid == 0) {
    const float xmin = sqrtf(smn[0]), mumax = sqrtf(smx[0]);
    const float d = xmin - mumax;
    flag[0] = (d > 0.f && gp[0] * d * d > UNDERFLOW_T) ? 1 : 0;
  }
}

// ---------------- gated prep kernels (skip all work on fast path) -----------

// Convert x fp32 -> bf16 (row-major). grid 8192 blocks of 256 (float4 each).
__global__ __launch_bounds__(256) void prep_x(const float* __restrict__ x,
                                              unsigned short* __restrict__ xb,
                                              const int* __restrict__ flag) {
  if (flag[0]) return;
  const size_t idx = (size_t)blockIdx.x * 256 + threadIdx.x;  // float4 slot
  const float4 v = reinterpret_cast<const float4*>(x)[idx];
  ushort4 o;
  o.x = f2bf(v.x); o.y = f2bf(v.y); o.z = f2bf(v.z); o.w = f2bf(v.w);
  reinterpret_cast<ushort4*>(xb)[idx] = o;
}

// Transpose + convert mu (K x N fp32) -> muT (N x K bf16).
__global__ __launch_bounds__(256) void prep_mu(const float* __restrict__ mu,
                                               unsigned short* __restrict__ muT,
                                               const int* __restrict__ flag) {
  if (flag[0]) return;
  __shared__ float tile[32][33];
  const int k0 = blockIdx.x * 32;  // K
  const int n0 = blockIdx.y * 32;  // N
  const int tx = threadIdx.x;      // 0..31
  const int ty = threadIdx.y;      // 0..7
#pragma unroll
  for (int r = 0; r < 32; r += 8)
    tile[r + ty][tx] = mu[(size_t)(k0 + r + ty) * N_COLS + n0 + tx];
  __syncthreads();
#pragma unroll
  for (int r = 0; r < 32; r += 8)
    muT[(size_t)(n0 + r + ty) * K_DIM + k0 + tx] = f2bf(tile[tx][r + ty]);
}

// ---------------- main GEMM + epilogue (or zero-fill on fast path) ----------
// 128x128 tile, 256 threads = 4 waves in 2x2, each wave 64x64 via 4x4 grid of
// 16x16x32 bf16 MFMA. BK=32. global_load_lds width-16 staging.

#define BM 128
#define BN 128
#define BK 32

__global__ __launch_bounds__(256) void rbf_gemm(
    const unsigned short* __restrict__ xb,   // B_ROWS x K_DIM bf16 bits
    const unsigned short* __restrict__ muT,  // N_COLS x K_DIM bf16 bits
    const float* __restrict__ xsq, const float* __restrict__ musq,
    const float* __restrict__ gamma_p, const int* __restrict__ flag,
    float* __restrict__ out) {
  const int tid = threadIdx.x;
  const int bm0 = blockIdx.x * BM;
  const int bn0 = blockIdx.y * BN;

  if (flag[0]) {
    // Guaranteed-underflow fast path: this tile of the output is exactly 0.
    const float4 z = {0.f, 0.f, 0.f, 0.f};
#pragma unroll
    for (int i = 0; i < 16; ++i) {
      const int slot = tid + i * 256;          // 0..4095 float4 slots
      const int row  = slot >> 5;              // 128 rows
      const int c4   = slot & 31;              // 32 float4 per row
      reinterpret_cast<float4*>(out + (size_t)(bm0 + row) * N_COLS + bn0)[c4] = z;
    }
    return;
  }

  __shared__ unsigned short la[BM * BK];  // 8 KB
  __shared__ unsigned short lb[BN * BK];  // 8 KB
  const int w = tid >> 6, l = tid & 63;
  const int wm = (w >> 1) * 64, wn = (w & 1) * 64;
  const int l15 = l & 15, l4 = l >> 4;

  f32x4 acc[4][4] = {};

  const int srow = tid >> 2;
  const int schunk = (tid & 3) * 8;
  const unsigned short* ga = xb + (size_t)(bm0 + srow) * K_DIM + schunk;
  const unsigned short* gb = muT + (size_t)(bn0 + srow) * K_DIM + schunk;
  unsigned short* la_dst = &la[tid * 8];
  unsigned short* lb_dst = &lb[tid * 8];

  for (int kk = 0; kk < K_DIM; kk += BK) {
    __builtin_amdgcn_global_load_lds((global_void*)(ga + kk),
                                     (lds_void*)la_dst, 16, 0, 0);
    __builtin_amdgcn_global_load_lds((global_void*)(ga + (size_t)64 * K_DIM + kk),
                                     (lds_void*)(la_dst + 64 * BK), 16, 0, 0);
    __builtin_amdgcn_global_load_lds((global_void*)(gb + kk),
                                     (lds_void*)lb_dst, 16, 0, 0);
    __builtin_amdgcn_global_load_lds((global_void*)(gb + (size_t)64 * K_DIM + kk),
                                     (lds_void*)(lb_dst + 64 * BK), 16, 0, 0);
    __syncthreads();

    bf16x8 af[4], bfr[4];
#pragma unroll
    for (int t = 0; t < 4; ++t) {
      af[t]  = *reinterpret_cast<const bf16x8*>(&la[(wm + t * 16 + l15) * BK + l4 * 8]);
      bfr[t] = *reinterpret_cast<const bf16x8*>(&lb[(wn + t * 16 + l15) * BK + l4 * 8]);
    }
#pragma unroll
    for (int mt = 0; mt < 4; ++mt)
#pragma unroll
      for (int nt = 0; nt < 4; ++nt)
        acc[mt][nt] = __builtin_amdgcn_mfma_f32_16x16x32_bf16(af[mt], bfr[nt],
                                                              acc[mt][nt], 0, 0, 0);
    __syncthreads();
  }

  const float g = gamma_p[0];
#pragma unroll
  for (int mt = 0; mt < 4; ++mt) {
    const int gm0 = bm0 + wm + mt * 16 + l4 * 4;
#pragma unroll
    for (int nt = 0; nt < 4; ++nt) {
      const int gn = bn0 + wn + nt * 16 + l15;
      const float ms = musq[gn];
#pragma unroll
      for (int r = 0; r < 4; ++r) {
        const int gm = gm0 + r;
        const float l2 = xsq[gm] + ms - 2.0f * acc[mt][nt][r];
        out[(size_t)gm * N_COLS + gn] = __expf(-g * l2);
      }
    }
  }
}

// ---------------- fallback (ws too small; fp32 direct) ----------------
__global__ __launch_bounds__(256) void rbf_naive(const float* __restrict__ x,
                                                 const float* __restrict__ mu,
                                                 const float* __restrict__ gp,
                                                 float* __restrict__ out) {
  const int u = blockIdx.x * 256 + threadIdx.x;
  const int b = blockIdx.y;
  const float* xr = x + (size_t)b * K_DIM;
  float dot = 0.f, xs = 0.f, ms = 0.f;
  for (int k = 0; k < K_DIM; ++k) {
    const float xv = xr[k];
    const float mv = mu[(size_t)k * N_COLS + u];
    dot += xv * mv; xs += xv * xv; ms += mv * mv;
  }
  out[(size_t)b * N_COLS + u] = __expf(-gp[0] * (xs + ms - 2.f * dot));
}

extern "C" void kernel_launch(void* const* d_in, const int* in_sizes, int n_in,
                              void* d_out, int out_size, void* d_ws, size_t ws_size,
                              hipStream_t stream) {
  const float* x  = (const float*)d_in[0];
  const float* mu = (const float*)d_in[1];
  const float* gp = (const float*)d_in[2];
  float* out = (float*)d_out;

  const size_t xb_bytes   = (size_t)B_ROWS * K_DIM * 2;   // 16 MB
  const size_t mut_bytes  = (size_t)N_COLS * K_DIM * 2;   //  8 MB
  const size_t xsq_bytes  = (size_t)B_ROWS * 4;
  const size_t musq_bytes = (size_t)N_COLS * 4;
  const size_t part_bytes = (size_t)4 * N_COLS * 4;
  const size_t need = xb_bytes + mut_bytes + xsq_bytes + musq_bytes +
                      part_bytes + 64;

  if (ws_size < need) {
    rbf_naive<<<dim3(N_COLS / 256, B_ROWS), 256, 0, stream>>>(x, mu, gp, out);
    return;
  }

  char* p = (char*)d_ws;
  unsigned short* xb  = (unsigned short*)p;            p += xb_bytes;
  unsigned short* muT = (unsigned short*)p;            p += mut_bytes;
  float* xsq  = (float*)p;                             p += xsq_bytes;
  float* musq = (float*)p;                             p += musq_bytes;
  float* part = (float*)p;                             p += part_bytes;
  int*   flag = (int*)p;

  xsq_k     <<<B_ROWS / 4, 256, 0, stream>>>(x, xsq);
  musq_part_k<<<dim3(N_COLS / 64, 4), 256, 0, stream>>>(mu, part);
  musq_sum_k<<<N_COLS / 256, 256, 0, stream>>>(part, musq);
  flag_k    <<<1, 256, 0, stream>>>(xsq, musq, gp, flag);
  prep_x    <<<B_ROWS * K_DIM / 4 / 256, 256, 0, stream>>>(x, xb, flag);
  prep_mu   <<<dim3(K_DIM / 32, N_COLS / 32), dim3(32, 8), 0, stream>>>(mu, muT, flag);
  rbf_gemm  <<<dim3(B_ROWS / BM, N_COLS / BN), 256, 0, stream>>>(
      xb, muT, xsq, musq, gp, flag, out);
}

// Round 3
// 215.252 us; speedup vs baseline: 1.2192x; 1.0121x over previous
//
#include <hip/hip_runtime.h>

// Problem constants (fixed by the reference setup)
#define B_ROWS 8192
#define K_DIM  1024
#define N_COLS 4096

// exp(-t) == 0.0f (below smallest subnormal 2^-149) for t > 150*ln2 = 103.97.
// Use 120 for margin against fp error in the norm computation.
#define UNDERFLOW_T 120.0f

typedef __attribute__((ext_vector_type(8))) __bf16 bf16x8;
typedef __attribute__((ext_vector_type(4))) float  f32x4;

typedef const __attribute__((address_space(1))) void global_void;
typedef __attribute__((address_space(3))) void lds_void;

__device__ inline unsigned short f2bf(float f) {
  unsigned int u = __float_as_uint(f);
  u += 0x7FFFu + ((u >> 16) & 1u);   // round-to-nearest-even
  return (unsigned short)(u >> 16);
}

// ---------------- fused norm kernel -----------------------------------------
// blocks [0, 2048):    ||x_row||^2, one wave per row (4 rows/block)
// blocks [2048, 2304): mu column partial sums: block b -> col-group (b&63),
//                      k-quarter (b>>6); writes part[kq*N + u]
__global__ __launch_bounds__(256) void norms_k(const float* __restrict__ x,
                                               const float* __restrict__ mu,
                                               float* __restrict__ xsq,
                                               float* __restrict__ part) {
  const int bid = blockIdx.x;
  const int tid = threadIdx.x;
  if (bid < 2048) {
    const int row  = (bid * 256 + tid) >> 6;
    const int lane = tid & 63;
    const float4* xr = reinterpret_cast<const float4*>(x + (size_t)row * K_DIM);
    float s = 0.f;
#pragma unroll
    for (int i = 0; i < 4; ++i) {
      const float4 v = xr[lane + i * 64];
      s += v.x * v.x + v.y * v.y + v.z * v.z + v.w * v.w;
    }
#pragma unroll
    for (int off = 32; off; off >>= 1) s += __shfl_down(s, off);
    if (lane == 0) xsq[row] = s;
  } else {
    const int b  = bid - 2048;
    const int tx = tid & 63;          // col within group of 64
    const int ty = tid >> 6;          // strip within quarter
    const int u  = (b & 63) * 64 + tx;
    const int k0 = (b >> 6) * 256 + ty * 64;
    float s = 0.f;
    for (int k = k0; k < k0 + 64; ++k) {
      const float v = mu[(size_t)k * N_COLS + u];
      s += v * v;
    }
    __shared__ float red[4][64];
    red[ty][tx] = s;
    __syncthreads();
    if (ty == 0)
      part[(size_t)(b >> 6) * N_COLS + u] =
          red[0][tx] + red[1][tx] + red[2][tx] + red[3][tx];
  }
}

// Single block: finalize musq[u] (needed by slow path), then
// flag = (min||x|| > max||mu||) && gamma*(min||x||-max||mu||)^2 > T.
// If set, every output provably underflows to exactly 0.0f (Cauchy-Schwarz:
// l2 >= (||x||-||mu||)^2 for every pair).
__global__ __launch_bounds__(256) void flag_k(const float* __restrict__ xsq,
                                              const float* __restrict__ part,
                                              float* __restrict__ musq,
                                              const float* __restrict__ gp,
                                              int* __restrict__ flag) {
  const int tid = threadIdx.x;
  float mn = 3.4e38f, mx = 0.f;
  for (int i = tid; i < B_ROWS; i += 256) mn = fminf(mn, xsq[i]);
  for (int u = tid; u < N_COLS; u += 256) {
    const float m = part[u] + part[N_COLS + u] + part[2 * N_COLS + u] +
                    part[3 * N_COLS + u];
    musq[u] = m;
    mx = fmaxf(mx, m);
  }
  __shared__ float smn[256], smx[256];
  smn[tid] = mn; smx[tid] = mx;
  __syncthreads();
  for (int s = 128; s; s >>= 1) {
    if (tid < s) {
      smn[tid] = fminf(smn[tid], smn[tid + s]);
      smx[tid] = fmaxf(smx[tid], smx[tid + s]);
    }
    __syncthreads();
  }
  if (tid == 0) {
    const float xmin = sqrtf(smn[0]), mumax = sqrtf(smx[0]);
    const float d = xmin - mumax;
    flag[0] = (d > 0.f && gp[0] * d * d > UNDERFLOW_T) ? 1 : 0;
  }
}

// ---------------- fused gated prep (skips all work on fast path) ------------
// blocks [0, 8192):      x fp32 -> bf16, one float4 per thread
// blocks [8192, 12288):  transpose+convert mu (K x N) -> muT (N x K bf16),
//                        32x32 tiles: b -> k-tile (b&31), n-tile (b>>5)
__global__ __launch_bounds__(256) void prep_k(const float* __restrict__ x,
                                              const float* __restrict__ mu,
                                              unsigned short* __restrict__ xb,
                                              unsigned short* __restrict__ muT,
                                              const int* __restrict__ flag) {
  if (flag[0]) return;
  const int bid = blockIdx.x;
  const int tid = threadIdx.x;
  if (bid < 8192) {
    const size_t idx = (size_t)bid * 256 + tid;  // float4 slot
    const float4 v = reinterpret_cast<const float4*>(x)[idx];
    ushort4 o;
    o.x = f2bf(v.x); o.y = f2bf(v.y); o.z = f2bf(v.z); o.w = f2bf(v.w);
    reinterpret_cast<ushort4*>(xb)[idx] = o;
  } else {
    __shared__ float tile[32][33];
    const int b  = bid - 8192;
    const int k0 = (b & 31) * 32;
    const int n0 = (b >> 5) * 32;
    const int tx = tid & 31;
    const int ty = tid >> 5;   // 0..7
#pragma unroll
    for (int r = 0; r < 32; r += 8)
      tile[r + ty][tx] = mu[(size_t)(k0 + r + ty) * N_COLS + n0 + tx];
    __syncthreads();
#pragma unroll
    for (int r = 0; r < 32; r += 8)
      muT[(size_t)(n0 + r + ty) * K_DIM + k0 + tx] = f2bf(tile[tx][r + ty]);
  }
}

// ---------------- main GEMM + epilogue (or zero-fill on fast path) ----------
// 128x128 tile, 256 threads = 4 waves in 2x2, each wave 64x64 via 4x4 grid of
// 16x16x32 bf16 MFMA. BK=32. global_load_lds width-16 staging.

#define BM 128
#define BN 128
#define BK 32

__global__ __launch_bounds__(256) void rbf_gemm(
    const unsigned short* __restrict__ xb,   // B_ROWS x K_DIM bf16 bits
    const unsigned short* __restrict__ muT,  // N_COLS x K_DIM bf16 bits
    const float* __restrict__ xsq, const float* __restrict__ musq,
    const float* __restrict__ gamma_p, const int* __restrict__ flag,
    float* __restrict__ out) {
  const int tid = threadIdx.x;
  const int bm0 = blockIdx.x * BM;
  const int bn0 = blockIdx.y * BN;

  if (flag[0]) {
    // Guaranteed-underflow fast path: this tile of the output is exactly 0.
    const float4 z = {0.f, 0.f, 0.f, 0.f};
#pragma unroll
    for (int i = 0; i < 16; ++i) {
      const int slot = tid + i * 256;          // 0..4095 float4 slots
      const int row  = slot >> 5;              // 128 rows
      const int c4   = slot & 31;              // 32 float4 per row
      reinterpret_cast<float4*>(out + (size_t)(bm0 + row) * N_COLS + bn0)[c4] = z;
    }
    return;
  }

  __shared__ unsigned short la[BM * BK];  // 8 KB
  __shared__ unsigned short lb[BN * BK];  // 8 KB
  const int w = tid >> 6, l = tid & 63;
  const int wm = (w >> 1) * 64, wn = (w & 1) * 64;
  const int l15 = l & 15, l4 = l >> 4;

  f32x4 acc[4][4] = {};

  const int srow = tid >> 2;
  const int schunk = (tid & 3) * 8;
  const unsigned short* ga = xb + (size_t)(bm0 + srow) * K_DIM + schunk;
  const unsigned short* gb = muT + (size_t)(bn0 + srow) * K_DIM + schunk;
  unsigned short* la_dst = &la[tid * 8];
  unsigned short* lb_dst = &lb[tid * 8];

  for (int kk = 0; kk < K_DIM; kk += BK) {
    __builtin_amdgcn_global_load_lds((global_void*)(ga + kk),
                                     (lds_void*)la_dst, 16, 0, 0);
    __builtin_amdgcn_global_load_lds((global_void*)(ga + (size_t)64 * K_DIM + kk),
                                     (lds_void*)(la_dst + 64 * BK), 16, 0, 0);
    __builtin_amdgcn_global_load_lds((global_void*)(gb + kk),
                                     (lds_void*)lb_dst, 16, 0, 0);
    __builtin_amdgcn_global_load_lds((global_void*)(gb + (size_t)64 * K_DIM + kk),
                                     (lds_void*)(lb_dst + 64 * BK), 16, 0, 0);
    __syncthreads();

    bf16x8 af[4], bfr[4];
#pragma unroll
    for (int t = 0; t < 4; ++t) {
      af[t]  = *reinterpret_cast<const bf16x8*>(&la[(wm + t * 16 + l15) * BK + l4 * 8]);
      bfr[t] = *reinterpret_cast<const bf16x8*>(&lb[(wn + t * 16 + l15) * BK + l4 * 8]);
    }
#pragma unroll
    for (int mt = 0; mt < 4; ++mt)
#pragma unroll
      for (int nt = 0; nt < 4; ++nt)
        acc[mt][nt] = __builtin_amdgcn_mfma_f32_16x16x32_bf16(af[mt], bfr[nt],
                                                              acc[mt][nt], 0, 0, 0);
    __syncthreads();
  }

  const float g = gamma_p[0];
#pragma unroll
  for (int mt = 0; mt < 4; ++mt) {
    const int gm0 = bm0 + wm + mt * 16 + l4 * 4;
#pragma unroll
    for (int nt = 0; nt < 4; ++nt) {
      const int gn = bn0 + wn + nt * 16 + l15;
      const float ms = musq[gn];
#pragma unroll
      for (int r = 0; r < 4; ++r) {
        const int gm = gm0 + r;
        const float l2 = xsq[gm] + ms - 2.0f * acc[mt][nt][r];
        out[(size_t)gm * N_COLS + gn] = __expf(-g * l2);
      }
    }
  }
}

// ---------------- fallback (ws too small; fp32 direct) ----------------
__global__ __launch_bounds__(256) void rbf_naive(const float* __restrict__ x,
                                                 const float* __restrict__ mu,
                                                 const float* __restrict__ gp,
                                                 float* __restrict__ out) {
  const int u = blockIdx.x * 256 + threadIdx.x;
  const int b = blockIdx.y;
  const float* xr = x + (size_t)b * K_DIM;
  float dot = 0.f, xs = 0.f, ms = 0.f;
  for (int k = 0; k < K_DIM; ++k) {
    const float xv = xr[k];
    const float mv = mu[(size_t)k * N_COLS + u];
    dot += xv * mv; xs += xv * xv; ms += mv * mv;
  }
  out[(size_t)b * N_COLS + u] = __expf(-gp[0] * (xs + ms - 2.f * dot));
}

extern "C" void kernel_launch(void* const* d_in, const int* in_sizes, int n_in,
                              void* d_out, int out_size, void* d_ws, size_t ws_size,
                              hipStream_t stream) {
  const float* x  = (const float*)d_in[0];
  const float* mu = (const float*)d_in[1];
  const float* gp = (const float*)d_in[2];
  float* out = (float*)d_out;

  const size_t xb_bytes   = (size_t)B_ROWS * K_DIM * 2;   // 16 MB
  const size_t mut_bytes  = (size_t)N_COLS * K_DIM * 2;   //  8 MB
  const size_t xsq_bytes  = (size_t)B_ROWS * 4;
  const size_t musq_bytes = (size_t)N_COLS * 4;
  const size_t part_bytes = (size_t)4 * N_COLS * 4;
  const size_t need = xb_bytes + mut_bytes + xsq_bytes + musq_bytes +
                      part_bytes + 64;

  if (ws_size < need) {
    rbf_naive<<<dim3(N_COLS / 256, B_ROWS), 256, 0, stream>>>(x, mu, gp, out);
    return;
  }

  char* p = (char*)d_ws;
  unsigned short* xb  = (unsigned short*)p;            p += xb_bytes;
  unsigned short* muT = (unsigned short*)p;            p += mut_bytes;
  float* xsq  = (float*)p;                             p += xsq_bytes;
  float* musq = (float*)p;                             p += musq_bytes;
  float* part = (float*)p;                             p += part_bytes;
  int*   flag = (int*)p;

  norms_k<<<2048 + 256, 256, 0, stream>>>(x, mu, xsq, part);
  flag_k <<<1, 256, 0, stream>>>(xsq, part, musq, gp, flag);
  prep_k <<<8192 + 4096, 256, 0, stream>>>(x, mu, xb, muT, flag);
  rbf_gemm<<<dim3(B_ROWS / BM, N_COLS / BN), 256, 0, stream>>>(
      xb, muT, xsq, musq, gp, flag, out);
}